// Round 22
// baseline (438.497 us; speedup 1.0000x reference)
//
#include <hip/hip_runtime.h>
#include <hip/hip_bf16.h>

#define B_ 128
#define T_ 300
#define TC_ 20
#define DW_ 16
#define DC_ 32
#define UC_ 32
#define UM_ 64
#define POS_ 20
#define PAR_ 8
#define VW_ 1834
#define VC_ 132
#define DIN_ 76
#define XS_ 80
#define NROW (B_*T_)
#define NXZB (B_*20)        // 2560 xz producer blocks (15 rows each)

typedef _Float16 half_t;
typedef half_t h2 __attribute__((ext_vector_type(2)));

__device__ __forceinline__ float fast_sig(float x){
  return __builtin_amdgcn_rcpf(1.f + __expf(-x));
}
__device__ __forceinline__ float fast_tanh(float x){
  return __builtin_amdgcn_rcpf(1.f + __expf(-2.f*x))*2.f - 1.f;
}
__device__ __forceinline__ float dot2u(unsigned int a, unsigned int b, float acc){
  union{unsigned int u; h2 h;} x, y; x.u = a; y.u = b;
#if __has_builtin(__builtin_amdgcn_fdot2)
  return __builtin_amdgcn_fdot2(x.h, y.h, acc, false);
#else
  return acc + (float)x.h.x*(float)y.h.x + (float)x.h.y*(float)y.h.y;
#endif
}
__device__ __forceinline__ float us2f(unsigned short s){
  union{unsigned short s; half_t h;} x; x.s = s; return (float)x.h;
}
__device__ __forceinline__ unsigned int packh2(float a, float b){
  union{h2 h; unsigned int u;} cv; cv.h = h2{(half_t)a,(half_t)b}; return cv.u;
}

// ---- fused prep + flag zeroing. Flat id over 105472 items.
__global__ void k_prep(const float* __restrict__ emb_char, const float* __restrict__ char_Wx,
                       const float* __restrict__ char_b,  const float* __restrict__ char_Wh,
                       const float* __restrict__ Whf, const float* __restrict__ Whb,
                       const float* __restrict__ Wxf, const float* __restrict__ Wxb,
                       float* __restrict__ xzc, half_t* __restrict__ chT,
                       half_t* __restrict__ whT_h, half_t* __restrict__ wxT_h,
                       int* __restrict__ flags){
  int id = blockIdx.x*256 + threadIdx.x;
  if (id < 16896){                              // xzc[v][j]
    int v = id >> 7, j = id & 127;
    float acc = char_b[j];
    #pragma unroll
    for (int k=0;k<DC_;k++) acc += emb_char[v*DC_+k]*char_Wx[k*(4*UC_)+j];
    xzc[id] = acc;
  } else if (id < 20992){                       // chT[j][k] = char_Wh[k][j]
    int t = id - 16896;
    int j = t >> 5, k = t & 31;
    chT[t] = (half_t)char_Wh[k*(4*UC_)+j];
  } else if (id < 53760){                       // whT_h[dir][j][k] = Wh[k][j]
    int t = id - 20992;
    int dirr = t >> 14, j = (t >> 6) & 255, k = t & 63;
    const float* W = dirr ? Whb : Whf;
    whT_h[t] = (half_t)W[k*(4*UM_)+j];
  } else if (id < 102912){                      // wxT_h[dir][jj][k], k pad 76->96
    int t = id - 53760;
    int dirr = t / 24576;
    int r = t % 24576;
    int jj = r / 96, k = r % 96;
    const float* W = dirr ? Wxb : Wxf;
    wxT_h[t] = (k < DIN_) ? (half_t)W[k*(4*UM_)+jj] : (half_t)0.f;
  } else if (id < 102912 + NXZB){               // ready flags
    flags[id - 102912] = 0;
  }
}

// ---- char LSTM + fused xfill (r20 champion form, (512,2)).
__global__ __launch_bounds__(512,2) void k_char(const int* __restrict__ char_in,
        const float* __restrict__ xzc, const half_t* __restrict__ chT,
        const int* __restrict__ word_in, const float* __restrict__ emb_wor,
        const float* __restrict__ pos, const float* __restrict__ par,
        float* __restrict__ x){
  __shared__ unsigned int hbuf2[8][16];   // h as h2 pairs, per wave
  __shared__ float2 zex[8][64];
  __shared__ int sidx[8*TC_];
  const int tid = threadIdx.x;
  const int w8 = tid >> 6;              // wave = seq slot 0..7
  const int lane = tid & 63;
  const int u = lane & 31;
  const int half = lane >> 5;
  const int seq = blockIdx.x*8 + w8;

  // fused xfill: cols [0,16) word emb, [48,68) pos, [68,76) par for 8 rows
  if (tid < 384){
    int r8 = tid / 48, c48 = tid % 48;
    int row = blockIdx.x*8 + r8;
    int col = (c48 < 16) ? c48 : (c48 + 32);
    float v;
    if (col < DW_)              v = emb_wor[word_in[row]*DW_ + col];
    else if (col < DW_+UC_+POS_) v = pos[row*POS_ + (col-(DW_+UC_))];
    else                         v = par[row*PAR_ + (col-(DW_+UC_+POS_))];
    x[row*XS_ + col] = v;
  }

  if (tid < 8*TC_) sidx[tid] = char_in[blockIdx.x*(8*TC_) + tid];
  if (half==0 && u<16) hbuf2[w8][u] = 0;

  unsigned int wa[16], wb[16];
  {
    const uint4* pa = reinterpret_cast<const uint4*>(chT + (half*64+u)*32);
    const uint4* pb = reinterpret_cast<const uint4*>(chT + (half*64+32+u)*32);
    #pragma unroll
    for (int q=0;q<4;q++){
      uint4 va = pa[q], vb = pb[q];
      wa[q*4+0]=va.x; wa[q*4+1]=va.y; wa[q*4+2]=va.z; wa[q*4+3]=va.w;
      wb[q*4+0]=vb.x; wb[q*4+1]=vb.y; wb[q*4+2]=vb.z; wb[q*4+3]=vb.w;
    }
  }
  __syncthreads();

  float h = 0.f, c = 0.f;
  int idx = sidx[w8*TC_ + 0];
  float za0 = xzc[idx*(4*UC_) + half*64 + u];
  float zb0 = xzc[idx*(4*UC_) + half*64 + 32 + u];

  for (int t=0; t<TC_; t++){
    int idxn = (t+1 < TC_) ? sidx[w8*TC_ + t+1] : 0;
    float zan = xzc[idxn*(4*UC_) + half*64 + u];        // prefetch
    float zbn = xzc[idxn*(4*UC_) + half*64 + 32 + u];

    float za = za0, zb = zb0;
    const uint4* hb = reinterpret_cast<const uint4*>(&hbuf2[w8][0]); // broadcast
    uint4 q0=hb[0], q1=hb[1], q2=hb[2], q3=hb[3];
    unsigned int hu[16] = {q0.x,q0.y,q0.z,q0.w, q1.x,q1.y,q1.z,q1.w,
                           q2.x,q2.y,q2.z,q2.w, q3.x,q3.y,q3.z,q3.w};
    #pragma unroll
    for (int k=0;k<16;k++){
      za = dot2u(wa[k], hu[k], za);
      zb = dot2u(wb[k], hu[k], zb);
    }
    zex[w8][lane] = make_float2(za, zb);  // half1 publishes (zg,zo)
    if (half == 0){
      float2 p = zex[w8][32+u];           // same wave, in-order DS
      float zi = za, zf = zb, zg = p.x, zo = p.y;
      float cn = fast_sig(zf)*c + fast_sig(zi)*fast_tanh(zg);
      float hn = fast_sig(zo)*fast_tanh(cn);
      bool m = (idx != 0);
      c = m ? cn : c;
      h = m ? hn : h;
      reinterpret_cast<half_t*>(&hbuf2[w8][0])[u] = (half_t)h;  // b16 write
    }
    idx = idxn; za0 = zan; zb0 = zbn;
  }
  if (half == 0) x[seq*XS_ + DW_ + u] = h;
}

// ---- FUSED xz GEMM producers + word-LSTM consumers, flag-synchronized.
// Blocks [0,NXZB): produce 15 xz rows for (batch bi, t-slice ts), slices
// interleaved (0,19,1,18,...) so chain heads are produced first; release
// flags[bi*20+ts]. Blocks [NXZB, NXZB+256): one chain wave each (r20 k_rnn),
// setprio(1), acquire-spin on the next slice's flag once per 15 steps.
__global__ __launch_bounds__(512,2) void k_xzrnn(const float* __restrict__ x,
      const half_t* __restrict__ wxT_h,
      const float* __restrict__ b_f, const float* __restrict__ b_b,
      half_t* __restrict__ xz,
      const int* __restrict__ word_in, const half_t* __restrict__ whT_h,
      half_t* __restrict__ hcat, int* __restrict__ flags){
  const int bid = blockIdx.x;
  if (bid < NXZB){
    // ---------------- xz producer ----------------
    __shared__ unsigned int xs[15][40];
    const int oi = bid / B_;            // 0..19 dispatch slot
    const int bi = bid % B_;            // batch
    const int ts = (oi & 1) ? (19 - (oi >> 1)) : (oi >> 1);
    const int row0 = bi*T_ + ts*15;
    const int j = threadIdx.x;
    const int jj = j & 255;
    const bool bwd = (j >= 256);
    const float bj = bwd ? b_b[jj] : b_f[jj];
    const int u = jj & 63, g = jj >> 6;
    const int ocol = (bwd ? 256 : 0) + u*4 + g;

    unsigned int wq[40];
    {
      const uint4* p = reinterpret_cast<const uint4*>(wxT_h + (size_t)((bwd?256:0)+jj)*96);
      #pragma unroll
      for (int q=0;q<10;q++){
        uint4 v = p[q];
        wq[q*4+0]=v.x; wq[q*4+1]=v.y; wq[q*4+2]=v.z; wq[q*4+3]=v.w;
      }
    }
    for (int i=j; i<15*40; i+=512){
      int r = i/40, q = i%40;
      unsigned int pk = 0;
      if (q < 38){
        float v0 = x[(size_t)(row0+r)*XS_ + 2*q];
        float v1 = x[(size_t)(row0+r)*XS_ + 2*q+1];
        pk = packh2(v0, v1);
      }
      xs[r][q] = pk;
    }
    __syncthreads();

    #pragma unroll
    for (int r=0; r<15; r++){
      const uint4* xr = reinterpret_cast<const uint4*>(&xs[r][0]);  // broadcast
      float acc = bj;
      #pragma unroll
      for (int q=0;q<10;q++){
        uint4 v = xr[q];
        acc = dot2u(wq[q*4+0], v.x, acc);
        acc = dot2u(wq[q*4+1], v.y, acc);
        acc = dot2u(wq[q*4+2], v.z, acc);
        acc = dot2u(wq[q*4+3], v.w, acc);
      }
      xz[(size_t)(row0+r)*512 + ocol] = (half_t)acc;
    }
    __syncthreads();                    // all stores issued (barrier drains vmcnt)
    if (j == 0){
      __threadfence();                  // device-scope release of xz rows
      __hip_atomic_store(&flags[bi*20 + ts], 1, __ATOMIC_RELEASE,
                         __HIP_MEMORY_SCOPE_AGENT);
    }
    return;
  }

  // ---------------- chain consumer (r20 k_rnn) ----------------
  const int chain = bid - NXZB;         // 0..255
  if (threadIdx.x >= 64) return;        // 1 wave per chain
  __shared__ half_t hbuf[64];
  __shared__ int wm[T_];
  const int l = threadIdx.x;
  const int dir = chain & 1;
  const int b = chain >> 1;

  unsigned int wt[4][32];
  #pragma unroll
  for (int g=0; g<4; g++){
    const uint4* p = reinterpret_cast<const uint4*>(whT_h + ((size_t)dir*256 + g*64 + l)*64);
    #pragma unroll
    for (int q=0;q<8;q++){
      uint4 v = p[q];
      wt[g][q*4+0]=v.x; wt[g][q*4+1]=v.y; wt[g][q*4+2]=v.z; wt[g][q*4+3]=v.w;
    }
  }
  for (int t=l; t<T_; t+=64) wm[t] = word_in[b*T_ + (dir ? (T_-1-t) : t)];
  hbuf[l] = (half_t)0.f;
  __builtin_amdgcn_s_setprio(1);        // favor chain wave over producers

  float h = 0.f, c_ = 0.f;
  int row0 = b*T_ + (dir ? T_-1 : 0);
  const half_t* xp = xz + (size_t)row0*512 + dir*256 + l*4;
  const ptrdiff_t dstep = dir ? -512 : 512;
  half_t* hout = hcat + (size_t)row0*(2*UM_) + dir*UM_ + l;
  const ptrdiff_t hstep = dir ? -(2*UM_) : (2*UM_);

  // wait for the first slice of this chain's direction
  {
    int ts0 = dir ? 19 : 0;
    const int* fp = flags + b*20 + ts0;
    while (__hip_atomic_load(fp, __ATOMIC_ACQUIRE, __HIP_MEMORY_SCOPE_AGENT) == 0)
      __builtin_amdgcn_s_sleep(8);
  }
  ushort4 z0 = *reinterpret_cast<const ushort4*>(xp);
  ushort4 z1 = *reinterpret_cast<const ushort4*>(xp + dstep);
  half_t hh[15];

  for (int outer=0; outer<20; ++outer){
    // wait for the next slice (covers this iter's prefetch lookahead)
    {
      int on = (outer+1 < 20) ? outer+1 : 19;
      int tsn = dir ? (19 - on) : on;
      const int* fp = flags + b*20 + tsn;
      while (__hip_atomic_load(fp, __ATOMIC_ACQUIRE, __HIP_MEMORY_SCOPE_AGENT) == 0)
        __builtin_amdgcn_s_sleep(8);
    }
    #pragma unroll
    for (int s=0; s<15; ++s){
      const int t = outer*15 + s;
      ushort4 z2 = {0,0,0,0};
      if (t+2 < T_) z2 = *reinterpret_cast<const ushort4*>(xp + 2*dstep); // prefetch

      const uint4* hb = reinterpret_cast<const uint4*>(hbuf);
      float ai0=0.f, ai1=0.f, af0=0.f, af1=0.f;
      float ag0=0.f, ag1=0.f, ao0=0.f, ao1=0.f;
      #pragma unroll
      for (int q=0;q<8;q++){
        uint4 hv = hb[q];
        ai0 = dot2u(wt[0][q*4+0], hv.x, ai0); ai1 = dot2u(wt[0][q*4+1], hv.y, ai1);
        ai0 = dot2u(wt[0][q*4+2], hv.z, ai0); ai1 = dot2u(wt[0][q*4+3], hv.w, ai1);
        af0 = dot2u(wt[1][q*4+0], hv.x, af0); af1 = dot2u(wt[1][q*4+1], hv.y, af1);
        af0 = dot2u(wt[1][q*4+2], hv.z, af0); af1 = dot2u(wt[1][q*4+3], hv.w, af1);
        ag0 = dot2u(wt[2][q*4+0], hv.x, ag0); ag1 = dot2u(wt[2][q*4+1], hv.y, ag1);
        ag0 = dot2u(wt[2][q*4+2], hv.z, ag0); ag1 = dot2u(wt[2][q*4+3], hv.w, ag1);
        ao0 = dot2u(wt[3][q*4+0], hv.x, ao0); ao1 = dot2u(wt[3][q*4+1], hv.y, ao1);
        ao0 = dot2u(wt[3][q*4+2], hv.z, ao0); ao1 = dot2u(wt[3][q*4+3], hv.w, ao1);
      }
      float zi = us2f(z0.x) + (ai0+ai1);
      float zf = us2f(z0.y) + (af0+af1);
      float zg = us2f(z0.z) + (ag0+ag1);
      float zo = us2f(z0.w) + (ao0+ao1);

      int mw = wm[t];
      float cn = fast_sig(zf)*c_ + fast_sig(zi)*fast_tanh(zg);
      float hn = fast_sig(zo)*fast_tanh(cn);
      if (mw != 0){ c_ = cn; h = hn; }
      half_t hq = (half_t)h;
      hbuf[l] = hq;                      // same-wave, in-order DS pipe
      hh[s] = hq;
      z0 = z1; z1 = z2; xp += dstep;
    }
    // burst-flush 15 coalesced stores (off the per-step critical path)
    #pragma unroll
    for (int s=0; s<15; ++s) hout[(ptrdiff_t)s * hstep] = hh[s];
    hout += (ptrdiff_t)15 * hstep;
  }
}

// ---- dense + softmax (hcat is f16)
__global__ void k_dense(const half_t* __restrict__ hcat, const float* __restrict__ W,
                        const float* __restrict__ bias, float* __restrict__ out){
  int r = blockIdx.x*256 + threadIdx.x;
  const uint4* h4 = reinterpret_cast<const uint4*>(hcat + (size_t)r*(2*UM_));
  float a0=bias[0], a1=bias[1], a2=bias[2], a3=bias[3];
  #pragma unroll
  for (int k8=0;k8<16;k8++){
    uint4 v = h4[k8];
    unsigned int uu[4] = {v.x, v.y, v.z, v.w};
    #pragma unroll
    for (int e=0;e<4;e++){
      int k = k8*8 + e*2;
      float hA = us2f((unsigned short)(uu[e] & 0xffffu));
      float hB = us2f((unsigned short)(uu[e] >> 16));
      a0 += hA*W[k*4+0] + hB*W[(k+1)*4+0];
      a1 += hA*W[k*4+1] + hB*W[(k+1)*4+1];
      a2 += hA*W[k*4+2] + hB*W[(k+1)*4+2];
      a3 += hA*W[k*4+3] + hB*W[(k+1)*4+3];
    }
  }
  float mx = fmaxf(fmaxf(a0,a1), fmaxf(a2,a3));
  float e0=__expf(a0-mx), e1=__expf(a1-mx), e2=__expf(a2-mx), e3=__expf(a3-mx);
  float s = __builtin_amdgcn_rcpf(e0+e1+e2+e3);
  out[r*4+0]=e0*s; out[r*4+1]=e1*s; out[r*4+2]=e2*s; out[r*4+3]=e3*s;
}

extern "C" void kernel_launch(void* const* d_in, const int* in_sizes, int n_in,
                              void* d_out, int out_size, void* d_ws, size_t ws_size,
                              hipStream_t stream) {
  const int*   word_in  = (const int*)  d_in[0];
  const int*   char_in  = (const int*)  d_in[1];
  const float* inp_pos  = (const float*)d_in[2];
  const float* inp_par  = (const float*)d_in[3];
  const float* emb_wor  = (const float*)d_in[4];
  const float* emb_char = (const float*)d_in[5];
  const float* char_Wx  = (const float*)d_in[6];
  const float* char_Wh  = (const float*)d_in[7];
  const float* char_b   = (const float*)d_in[8];
  const float* fwd_Wx   = (const float*)d_in[9];
  const float* fwd_Wh   = (const float*)d_in[10];
  const float* fwd_b    = (const float*)d_in[11];
  const float* bwd_Wx   = (const float*)d_in[12];
  const float* bwd_Wh   = (const float*)d_in[13];
  const float* bwd_b    = (const float*)d_in[14];
  const float* dense_W  = (const float*)d_in[15];
  const float* dense_b  = (const float*)d_in[16];
  float* out = (float*)d_out;

  char* base = (char*)d_ws;
  float*  xw    = (float*)base;            base += (size_t)NROW*XS_*4;
  half_t* hcat  = (half_t*)base;           base += (size_t)NROW*128*2;
  float*  xzc   = (float*)base;            base += (size_t)VC_*128*4;
  half_t* chT   = (half_t*)base;           base += 128*32*2;
  half_t* whT_h = (half_t*)base;           base += 2*256*64*2;
  half_t* wxT_h = (half_t*)base;           base += 2*256*96*2;
  int*    flags = (int*)base;              base += NXZB*4;
  half_t* xzw   = (half_t*)base;

  k_prep <<<412, 256, 0, stream>>>(emb_char, char_Wx, char_b, char_Wh,
                                   fwd_Wh, bwd_Wh, fwd_Wx, bwd_Wx,
                                   xzc, chT, whT_h, wxT_h, flags);
  k_char <<<NROW/8, 512, 0, stream>>>(char_in, xzc, chT,
                                      word_in, emb_wor, inp_pos, inp_par, xw);
  k_xzrnn<<<NXZB + 2*B_, 512, 0, stream>>>(xw, wxT_h, fwd_b, bwd_b, xzw,
                                           word_in, whT_h, hcat, flags);
  k_dense<<<NROW/256, 256, 0, stream>>>(hcat, dense_W, dense_b, out);
}

// Round 23
// 289.356 us; speedup vs baseline: 1.5154x; 1.5154x over previous
//
#include <hip/hip_runtime.h>
#include <hip/hip_bf16.h>

#define B_ 128
#define T_ 300
#define TC_ 20
#define DW_ 16
#define DC_ 32
#define UC_ 32
#define UM_ 64
#define POS_ 20
#define PAR_ 8
#define VW_ 1834
#define VC_ 132
#define DIN_ 76
#define XS_ 80
#define NROW (B_*T_)

typedef _Float16 half_t;
typedef half_t h2 __attribute__((ext_vector_type(2)));

__device__ __forceinline__ float fast_sig(float x){
  return __builtin_amdgcn_rcpf(1.f + __expf(-x));
}
__device__ __forceinline__ float fast_tanh(float x){
  return __builtin_amdgcn_rcpf(1.f + __expf(-2.f*x))*2.f - 1.f;
}
__device__ __forceinline__ float dot2u(unsigned int a, unsigned int b, float acc){
  union{unsigned int u; h2 h;} x, y; x.u = a; y.u = b;
#if __has_builtin(__builtin_amdgcn_fdot2)
  return __builtin_amdgcn_fdot2(x.h, y.h, acc, false);
#else
  return acc + (float)x.h.x*(float)y.h.x + (float)x.h.y*(float)y.h.y;
#endif
}
__device__ __forceinline__ float us2f(unsigned short s){
  union{unsigned short s; half_t h;} x; x.s = s; return (float)x.h;
}
__device__ __forceinline__ unsigned int packh2(float a, float b){
  union{h2 h; unsigned int u;} cv; cv.h = h2{(half_t)a,(half_t)b}; return cv.u;
}

// ---- fused prep: xzc (132x128 f32) | chT (128x32 f16) | whT_h (2x256x64 f16)
//                  | wxT_h (2x256x96 f16).  Flat id over 102912 items.
__global__ void k_prep(const float* __restrict__ emb_char, const float* __restrict__ char_Wx,
                       const float* __restrict__ char_b,  const float* __restrict__ char_Wh,
                       const float* __restrict__ Whf, const float* __restrict__ Whb,
                       const float* __restrict__ Wxf, const float* __restrict__ Wxb,
                       float* __restrict__ xzc, half_t* __restrict__ chT,
                       half_t* __restrict__ whT_h, half_t* __restrict__ wxT_h){
  int id = blockIdx.x*256 + threadIdx.x;
  if (id < 16896){                              // xzc[v][j]
    int v = id >> 7, j = id & 127;
    float acc = char_b[j];
    #pragma unroll
    for (int k=0;k<DC_;k++) acc += emb_char[v*DC_+k]*char_Wx[k*(4*UC_)+j];
    xzc[id] = acc;
  } else if (id < 20992){                       // chT[j][k] = char_Wh[k][j]
    int t = id - 16896;
    int j = t >> 5, k = t & 31;
    chT[t] = (half_t)char_Wh[k*(4*UC_)+j];
  } else if (id < 53760){                       // whT_h[dir][j][k] = Wh[k][j]
    int t = id - 20992;
    int dirr = t >> 14, j = (t >> 6) & 255, k = t & 63;
    const float* W = dirr ? Whb : Whf;
    whT_h[t] = (half_t)W[k*(4*UM_)+j];
  } else {                                      // wxT_h[dir][jj][k], k pad 76->96
    int t = id - 53760;
    int dirr = t / 24576;
    int r = t % 24576;
    int jj = r / 96, k = r % 96;
    const float* W = dirr ? Wxb : Wxf;
    wxT_h[t] = (k < DIN_) ? (half_t)W[k*(4*UM_)+jj] : (half_t)0.f;
  }
}

// ---- char LSTM + fused xfill. wave = 1 seq; lane u&31 = unit, lane>>5 = half.
// half0: gates i,f; half1: g,o. 32 packed-f16 weight uints/thread, builtin dot2.
__global__ __launch_bounds__(512,2) void k_char(const int* __restrict__ char_in,
        const float* __restrict__ xzc, const half_t* __restrict__ chT,
        const int* __restrict__ word_in, const float* __restrict__ emb_wor,
        const float* __restrict__ pos, const float* __restrict__ par,
        float* __restrict__ x){
  __shared__ unsigned int hbuf2[8][16];   // h as h2 pairs, per wave
  __shared__ float2 zex[8][64];
  __shared__ int sidx[8*TC_];
  const int tid = threadIdx.x;
  const int w8 = tid >> 6;              // wave = seq slot 0..7
  const int lane = tid & 63;
  const int u = lane & 31;
  const int half = lane >> 5;
  const int seq = blockIdx.x*8 + w8;

  // fused xfill: cols [0,16) word emb, [48,68) pos, [68,76) par for 8 rows
  if (tid < 384){
    int r8 = tid / 48, c48 = tid % 48;
    int row = blockIdx.x*8 + r8;
    int col = (c48 < 16) ? c48 : (c48 + 32);
    float v;
    if (col < DW_)              v = emb_wor[word_in[row]*DW_ + col];
    else if (col < DW_+UC_+POS_) v = pos[row*POS_ + (col-(DW_+UC_))];
    else                         v = par[row*PAR_ + (col-(DW_+UC_+POS_))];
    x[row*XS_ + col] = v;
  }

  if (tid < 8*TC_) sidx[tid] = char_in[blockIdx.x*(8*TC_) + tid];
  if (half==0 && u<16) hbuf2[w8][u] = 0;

  // cols: a = half*64+u, b = half*64+32+u; chT[col*32+k] -> 16 uints each
  unsigned int wa[16], wb[16];
  {
    const uint4* pa = reinterpret_cast<const uint4*>(chT + (half*64+u)*32);
    const uint4* pb = reinterpret_cast<const uint4*>(chT + (half*64+32+u)*32);
    #pragma unroll
    for (int q=0;q<4;q++){
      uint4 va = pa[q], vb = pb[q];
      wa[q*4+0]=va.x; wa[q*4+1]=va.y; wa[q*4+2]=va.z; wa[q*4+3]=va.w;
      wb[q*4+0]=vb.x; wb[q*4+1]=vb.y; wb[q*4+2]=vb.z; wb[q*4+3]=vb.w;
    }
  }
  __syncthreads();

  float h = 0.f, c = 0.f;
  int idx = sidx[w8*TC_ + 0];
  float za0 = xzc[idx*(4*UC_) + half*64 + u];
  float zb0 = xzc[idx*(4*UC_) + half*64 + 32 + u];

  for (int t=0; t<TC_; t++){
    int idxn = (t+1 < TC_) ? sidx[w8*TC_ + t+1] : 0;
    float zan = xzc[idxn*(4*UC_) + half*64 + u];        // prefetch
    float zbn = xzc[idxn*(4*UC_) + half*64 + 32 + u];

    float za = za0, zb = zb0;
    const uint4* hb = reinterpret_cast<const uint4*>(&hbuf2[w8][0]); // broadcast
    uint4 q0=hb[0], q1=hb[1], q2=hb[2], q3=hb[3];
    unsigned int hu[16] = {q0.x,q0.y,q0.z,q0.w, q1.x,q1.y,q1.z,q1.w,
                           q2.x,q2.y,q2.z,q2.w, q3.x,q3.y,q3.z,q3.w};
    #pragma unroll
    for (int k=0;k<16;k++){
      za = dot2u(wa[k], hu[k], za);
      zb = dot2u(wb[k], hu[k], zb);
    }
    zex[w8][lane] = make_float2(za, zb);  // half1 publishes (zg,zo)
    if (half == 0){
      float2 p = zex[w8][32+u];           // same wave, in-order DS
      float zi = za, zf = zb, zg = p.x, zo = p.y;
      float cn = fast_sig(zf)*c + fast_sig(zi)*fast_tanh(zg);
      float hn = fast_sig(zo)*fast_tanh(cn);
      bool m = (idx != 0);
      c = m ? cn : c;
      h = m ? hn : h;
      reinterpret_cast<half_t*>(&hbuf2[w8][0])[u] = (half_t)h;  // b16 write
    }
    idx = idxn; za0 = zan; zb0 = zbn;
  }
  if (half == 0) x[seq*XS_ + DW_ + u] = h;
}

// ---- xz GEMM via dot2: x staged as packed f16 in LDS (broadcast reads),
// 40 weight uints/thread. Output [row][dir*256 + u*4 + g] f16.
__global__ __launch_bounds__(512,2) void k_xz(const float* __restrict__ x,
      const half_t* __restrict__ wxT_h,
      const float* __restrict__ b_f, const float* __restrict__ b_b,
      half_t* __restrict__ xz){
  __shared__ unsigned int xs[16][40];     // 16 rows x 80 halves (76+pad)
  const int j = threadIdx.x;
  const int jj = j & 255;
  const bool bwd = (j >= 256);
  const float bj = bwd ? b_b[jj] : b_f[jj];
  const int u = jj & 63, g = jj >> 6;
  const int ocol = (bwd ? 256 : 0) + u*4 + g;

  unsigned int wq[40];
  {
    const uint4* p = reinterpret_cast<const uint4*>(wxT_h + (size_t)((bwd?256:0)+jj)*96);
    #pragma unroll
    for (int q=0;q<10;q++){
      uint4 v = p[q];
      wq[q*4+0]=v.x; wq[q*4+1]=v.y; wq[q*4+2]=v.z; wq[q*4+3]=v.w;
    }
  }

  const int rowbase = blockIdx.x*16;
  for (int i=j; i<16*40; i+=512){
    int r = i/40, q = i%40;
    unsigned int pk = 0;
    if (q < 38){
      float v0 = x[(size_t)(rowbase+r)*XS_ + 2*q];
      float v1 = x[(size_t)(rowbase+r)*XS_ + 2*q+1];
      pk = packh2(v0, v1);
    }
    xs[r][q] = pk;
  }
  __syncthreads();

  for (int r=0; r<16; r++){
    const uint4* xr = reinterpret_cast<const uint4*>(&xs[r][0]);  // broadcast
    float acc = bj;
    #pragma unroll
    for (int q=0;q<10;q++){
      uint4 v = xr[q];
      acc = dot2u(wq[q*4+0], v.x, acc);
      acc = dot2u(wq[q*4+1], v.y, acc);
      acc = dot2u(wq[q*4+2], v.z, acc);
      acc = dot2u(wq[q*4+3], v.w, acc);
    }
    xz[(size_t)(rowbase+r)*512 + ocol] = (half_t)acc;
  }
}

// ---- word LSTM: ONE WAVE per (batch,dir), batched h-stores (burst 10),
// builtin dot2 (AGPR-sourced, no copies). Zero barriers in the step loop.
// r14 champion structure; hcat stored f16.
__global__ __launch_bounds__(64,1) void k_rnn(const half_t* __restrict__ xz,
      const int* __restrict__ word_in, const half_t* __restrict__ whT_h,
      half_t* __restrict__ hcat){
  __shared__ half_t hbuf[64];
  __shared__ int wm[T_];
  const int l = threadIdx.x;
  const int dir = blockIdx.x & 1;
  const int b = blockIdx.x >> 1;

  // weights: column (gate g, unit l) -> 32 uints each, 128 total
  unsigned int wt[4][32];
  #pragma unroll
  for (int g=0; g<4; g++){
    const uint4* p = reinterpret_cast<const uint4*>(whT_h + ((size_t)dir*256 + g*64 + l)*64);
    #pragma unroll
    for (int q=0;q<8;q++){
      uint4 v = p[q];
      wt[g][q*4+0]=v.x; wt[g][q*4+1]=v.y; wt[g][q*4+2]=v.z; wt[g][q*4+3]=v.w;
    }
  }
  for (int t=l; t<T_; t+=64) wm[t] = word_in[b*T_ + (dir ? (T_-1-t) : t)];
  hbuf[l] = (half_t)0.f;
  __syncthreads();

  float h = 0.f, c_ = 0.f;
  int row0 = b*T_ + (dir ? T_-1 : 0);
  const half_t* xp = xz + (size_t)row0*512 + dir*256 + l*4;
  const ptrdiff_t dstep = dir ? -512 : 512;
  half_t* hout = hcat + (size_t)row0*(2*UM_) + dir*UM_ + l;
  const ptrdiff_t hstep = dir ? -(2*UM_) : (2*UM_);

  ushort4 z0 = *reinterpret_cast<const ushort4*>(xp);
  ushort4 z1 = *reinterpret_cast<const ushort4*>(xp + dstep);
  half_t hh[10];

  for (int outer=0; outer<30; ++outer){
    #pragma unroll
    for (int s=0; s<10; ++s){
      const int t = outer*10 + s;
      ushort4 z2 = {0,0,0,0};
      if (t+2 < T_) z2 = *reinterpret_cast<const ushort4*>(xp + 2*dstep); // prefetch

      const uint4* hb = reinterpret_cast<const uint4*>(hbuf);
      float ai0=0.f, ai1=0.f, af0=0.f, af1=0.f;
      float ag0=0.f, ag1=0.f, ao0=0.f, ao1=0.f;
      #pragma unroll
      for (int q=0;q<8;q++){
        uint4 hv = hb[q];
        ai0 = dot2u(wt[0][q*4+0], hv.x, ai0); ai1 = dot2u(wt[0][q*4+1], hv.y, ai1);
        ai0 = dot2u(wt[0][q*4+2], hv.z, ai0); ai1 = dot2u(wt[0][q*4+3], hv.w, ai1);
        af0 = dot2u(wt[1][q*4+0], hv.x, af0); af1 = dot2u(wt[1][q*4+1], hv.y, af1);
        af0 = dot2u(wt[1][q*4+2], hv.z, af0); af1 = dot2u(wt[1][q*4+3], hv.w, af1);
        ag0 = dot2u(wt[2][q*4+0], hv.x, ag0); ag1 = dot2u(wt[2][q*4+1], hv.y, ag1);
        ag0 = dot2u(wt[2][q*4+2], hv.z, ag0); ag1 = dot2u(wt[2][q*4+3], hv.w, ag1);
        ao0 = dot2u(wt[3][q*4+0], hv.x, ao0); ao1 = dot2u(wt[3][q*4+1], hv.y, ao1);
        ao0 = dot2u(wt[3][q*4+2], hv.z, ao0); ao1 = dot2u(wt[3][q*4+3], hv.w, ao1);
      }
      float zi = us2f(z0.x) + (ai0+ai1);
      float zf = us2f(z0.y) + (af0+af1);
      float zg = us2f(z0.z) + (ag0+ag1);
      float zo = us2f(z0.w) + (ao0+ao1);

      int mw = wm[t];
      float cn = fast_sig(zf)*c_ + fast_sig(zi)*fast_tanh(zg);
      float hn = fast_sig(zo)*fast_tanh(cn);
      if (mw != 0){ c_ = cn; h = hn; }
      half_t hq = (half_t)h;
      hbuf[l] = hq;                        // same-wave, in-order DS pipe
      hh[s] = hq;
      z0 = z1; z1 = z2; xp += dstep;
    }
    // burst-flush 10 coalesced stores (off the per-step critical path)
    #pragma unroll
    for (int s=0; s<10; ++s) hout[(ptrdiff_t)s * hstep] = hh[s];
    hout += (ptrdiff_t)10 * hstep;
  }
}

// ---- dense + softmax (hcat is f16)
__global__ void k_dense(const half_t* __restrict__ hcat, const float* __restrict__ W,
                        const float* __restrict__ bias, float* __restrict__ out){
  int r = blockIdx.x*256 + threadIdx.x;
  const uint4* h4 = reinterpret_cast<const uint4*>(hcat + (size_t)r*(2*UM_));
  float a0=bias[0], a1=bias[1], a2=bias[2], a3=bias[3];
  #pragma unroll
  for (int k8=0;k8<16;k8++){
    uint4 v = h4[k8];
    unsigned int uu[4] = {v.x, v.y, v.z, v.w};
    #pragma unroll
    for (int e=0;e<4;e++){
      int k = k8*8 + e*2;
      float hA = us2f((unsigned short)(uu[e] & 0xffffu));
      float hB = us2f((unsigned short)(uu[e] >> 16));
      a0 += hA*W[k*4+0] + hB*W[(k+1)*4+0];
      a1 += hA*W[k*4+1] + hB*W[(k+1)*4+1];
      a2 += hA*W[k*4+2] + hB*W[(k+1)*4+2];
      a3 += hA*W[k*4+3] + hB*W[(k+1)*4+3];
    }
  }
  float mx = fmaxf(fmaxf(a0,a1), fmaxf(a2,a3));
  float e0=__expf(a0-mx), e1=__expf(a1-mx), e2=__expf(a2-mx), e3=__expf(a3-mx);
  float s = __builtin_amdgcn_rcpf(e0+e1+e2+e3);
  out[r*4+0]=e0*s; out[r*4+1]=e1*s; out[r*4+2]=e2*s; out[r*4+3]=e3*s;
}

extern "C" void kernel_launch(void* const* d_in, const int* in_sizes, int n_in,
                              void* d_out, int out_size, void* d_ws, size_t ws_size,
                              hipStream_t stream) {
  const int*   word_in  = (const int*)  d_in[0];
  const int*   char_in  = (const int*)  d_in[1];
  const float* inp_pos  = (const float*)d_in[2];
  const float* inp_par  = (const float*)d_in[3];
  const float* emb_wor  = (const float*)d_in[4];
  const float* emb_char = (const float*)d_in[5];
  const float* char_Wx  = (const float*)d_in[6];
  const float* char_Wh  = (const float*)d_in[7];
  const float* char_b   = (const float*)d_in[8];
  const float* fwd_Wx   = (const float*)d_in[9];
  const float* fwd_Wh   = (const float*)d_in[10];
  const float* fwd_b    = (const float*)d_in[11];
  const float* bwd_Wx   = (const float*)d_in[12];
  const float* bwd_Wh   = (const float*)d_in[13];
  const float* bwd_b    = (const float*)d_in[14];
  const float* dense_W  = (const float*)d_in[15];
  const float* dense_b  = (const float*)d_in[16];
  float* out = (float*)d_out;

  char* base = (char*)d_ws;
  float*  xw    = (float*)base;            base += (size_t)NROW*XS_*4;
  half_t* hcat  = (half_t*)base;           base += (size_t)NROW*128*2;
  float*  xzc   = (float*)base;            base += (size_t)VC_*128*4;
  half_t* chT   = (half_t*)base;           base += 128*32*2;
  half_t* whT_h = (half_t*)base;           base += 2*256*64*2;
  half_t* wxT_h = (half_t*)base;           base += 2*256*96*2;
  half_t* xzw   = (half_t*)base;

  k_prep <<<402, 256, 0, stream>>>(emb_char, char_Wx, char_b, char_Wh,
                                   fwd_Wh, bwd_Wh, fwd_Wx, bwd_Wx,
                                   xzc, chT, whT_h, wxT_h);
  k_char <<<NROW/8, 512, 0, stream>>>(char_in, xzc, chT,
                                      word_in, emb_wor, inp_pos, inp_par, xw);
  k_xz   <<<NROW/16, 512, 0, stream>>>(xw, wxT_h, fwd_b, bwd_b, xzw);
  k_rnn  <<<2*B_, 64, 0, stream>>>(xzw, word_in, whT_h, hcat);
  k_dense<<<NROW/256, 256, 0, stream>>>(hcat, dense_W, dense_b, out);
}